// Round 11
// baseline (293.642 us; speedup 1.0000x reference)
//
#include <hip/hip_runtime.h>

#define DEV_INLINE __device__ __forceinline__

constexpr int NF = 26;   // input features
constexpr int H1 = 24;   // layer-1 hidden
constexpr int H2 = 8;    // layer-2 hidden
constexpr int T  = 5;    // sequence length
constexpr int BPW  = 32; // batch rows per wave (2 M-tiles of 16)
constexpr int ROWU = 20; // uints per LDS h-row (40 f16 = 80 B)

typedef _Float16 f16x8 __attribute__((ext_vector_type(8)));
typedef float    f32x4 __attribute__((ext_vector_type(4)));
typedef __fp16   fp16x2 __attribute__((ext_vector_type(2)));

union Q { uint4 u; f16x8 h; };

DEV_INLINE float fast_rcp(float x) { return __builtin_amdgcn_rcpf(x); }
DEV_INLINE float fast_sigmoid(float x) { return fast_rcp(1.0f + __expf(-x)); }
DEV_INLINE float fast_tanh(float x) {
    return fmaf(2.0f, fast_rcp(1.0f + __expf(-2.0f * x)), -1.0f);
}
DEV_INLINE float cellh(float i_, float f_, float g_, float o_, float& c) {
    const float ig = fast_sigmoid(i_), fg = fast_sigmoid(f_);
    const float gg = fast_tanh(g_),    og = fast_sigmoid(o_);
    c = fmaf(fg, c, ig * gg);
    return og * fast_tanh(c);
}
DEV_INLINE uint pkrtz(float a, float b) {
    union { uint u; fp16x2 p; } v; v.p = __builtin_amdgcn_cvt_pkrtz(a, b); return v.u;
}

// R11: weight B-fragments live in block-shared LDS (staged once, cooperatively)
// instead of 80 per-wave VGPRs -> unified reg footprint <=128 -> 4 waves/SIMD.
// sW[tile][lane] = 16B fragment; tiles 0..7 Bih1, 8..15 Bhh1, 16..19 Bc2.
// Per-lane packing convention identical to R9/R10 (HW-validated):
//   lane (q,r16): B[k=8q..8q+7][col j], L1 cols gate-major (i|f|g|o)*32+j.
// sH wave-private [h1|h2] f16 state; NO __syncthreads in the t-loop (one after
// staging). Final h2 read back from sH (no h2o regs).

__global__ __launch_bounds__(256, 4) void lstm2_mfma(
    const float* __restrict__ x,
    const float* __restrict__ w_ih1, const float* __restrict__ w_hh1,
    const float* __restrict__ b_ih1, const float* __restrict__ b_hh1,
    const float* __restrict__ w_ih2, const float* __restrict__ w_hh2,
    const float* __restrict__ b_ih2, const float* __restrict__ b_hh2,
    float* __restrict__ out, int batch)
{
    __shared__ uint4 sW[20][64];         // 20 KiB: weight B-fragments, block-shared
    __shared__ uint  sH[4][BPW * ROWU];  // 10 KiB: [h1|h2] f16 state, wave-private

    const int tid = threadIdx.x;
    const int w   = tid >> 6;        // wave id
    const int l   = tid & 63;        // lane
    const int q   = l >> 4;          // quarter (k-slice 8q..8q+7)
    const int r16 = l & 15;          // row (A) / col (B,C) within 16x16 tile
    const int wb  = blockIdx.x * 128 + w * BPW;

    // ---- zero sH (h=0 init); wave-private ----
    for (int i = l; i < BPW * ROWU; i += 64) sH[w][i] = 0u;

    // ---- issue x(t=0) loads early (complete during weight staging) ----
    int row0 = wb + r16;      if (row0 > batch - 1) row0 = batch - 1;
    int row1 = wb + 16 + r16; if (row1 > batch - 1) row1 = batch - 1;
    const float* __restrict__ xp0 = x + (size_t)row0 * (T * NF) + q * 8;
    const float* __restrict__ xp1 = x + (size_t)row1 * (T * NF) + q * 8;
    const bool q3 = (q == 3);
    const float2 z2 = make_float2(0.0f, 0.0f);

    float2 xr_[2][4];
    #pragma unroll
    for (int m = 0; m < 2; ++m) {
        const float* __restrict__ p = m ? xp1 : xp0;
        xr_[m][0] = *reinterpret_cast<const float2*>(p);
        xr_[m][1] = q3 ? z2 : *reinterpret_cast<const float2*>(p + 2);
        xr_[m][2] = q3 ? z2 : *reinterpret_cast<const float2*>(p + 4);
        xr_[m][3] = q3 ? z2 : *reinterpret_cast<const float2*>(p + 6);
    }

    // ---- cooperative weight staging: wave w does tiles w, w+4, ... ----
    for (int tile = w; tile < 20; tile += 4) {
        f16x8 bf;
        if (tile < 16) {
            const int tau  = tile & 7;
            const int gate = tau >> 1, j = (tau & 1) * 16 + r16;
            const bool jv  = (j < H1);
            const int row  = gate * H1 + (jv ? j : 0);
            const bool ih  = (tile < 8);
            #pragma unroll
            for (int e = 0; e < 8; ++e) {
                const int k = q * 8 + e;
                float v = 0.0f;
                if (ih) { if (jv && k < NF) v = w_ih1[row * NF + k]; }
                else    { if (jv && k < H1) v = w_hh1[row * H1 + k]; }
                bf[e] = (_Float16)v;
            }
        } else {
            const int t2  = tile - 16;
            const bool jv = (r16 < H2);
            const int row = t2 * H2 + (jv ? r16 : 0);
            #pragma unroll
            for (int e = 0; e < 8; ++e) {
                const int k = q * 8 + e;
                float v = 0.0f;
                if (jv) v = (k < H1) ? w_ih2[row * H1 + k] : w_hh2[row * H2 + (k - H1)];
                bf[e] = (_Float16)v;
            }
        }
        Q u; u.h = bf;
        sW[tile][l] = u.u;
    }

    // ---- biases in regs (12 scalars, per-lane) ----
    float bias1[8], bias2[4];
    #pragma unroll
    for (int tau = 0; tau < 8; ++tau) {
        const int gate = tau >> 1, j = (tau & 1) * 16 + r16;
        const bool jv  = (j < H1);
        const int row  = gate * H1 + (jv ? j : 0);
        bias1[tau] = jv ? (b_ih1[row] + b_hh1[row]) : 0.0f;
    }
    #pragma unroll
    for (int t2 = 0; t2 < 4; ++t2) {
        const bool jv = (r16 < H2);
        const int row = t2 * H2 + (jv ? r16 : 0);
        bias2[t2] = jv ? (b_ih2[row] + b_hh2[row]) : 0.0f;
    }

    __syncthreads();   // weights visible to all waves (only barrier in kernel)

    float c1a[2][4] = {}, c1b[2][4] = {}, c2s[2][4] = {};
    const uint4* HQ = reinterpret_cast<const uint4*>(&sH[w][0]);
    _Float16*   Hh  = reinterpret_cast<_Float16*>(&sH[w][0]);

    #pragma unroll 1
    for (int t = 0; t < T; ++t) {
        // ---- convert raw x -> A-frags ----
        Q xa[2];
        #pragma unroll
        for (int m = 0; m < 2; ++m) {
            uint4 u;
            u.x = pkrtz(xr_[m][0].x, xr_[m][0].y);
            u.y = pkrtz(xr_[m][1].x, xr_[m][1].y);
            u.z = pkrtz(xr_[m][2].x, xr_[m][2].y);
            u.w = pkrtz(xr_[m][3].x, xr_[m][3].y);
            xa[m].u = u;
        }

        // ---- read [h1|h2](prev t) A-frags ----
        Q ha[2];
        #pragma unroll
        for (int m = 0; m < 2; ++m) ha[m].u = HQ[(m * 16 + r16) * 5 + q];
        __builtin_amdgcn_sched_barrier(0);   // frag reads before h1 overwrite (WAR)

        // ---- layer 1: weights from LDS, 16 MFMA per M-tile, cells ----
        #pragma unroll
        for (int m = 0; m < 2; ++m) {
            f32x4 acc[8];
            #pragma unroll
            for (int tau = 0; tau < 8; ++tau) {
                const float b = bias1[tau];
                f32x4 bv = {b, b, b, b};
                acc[tau] = bv;
            }
            #pragma unroll
            for (int tau = 0; tau < 8; ++tau) {
                Q wi, wh;
                wi.u = sW[tau][l];          // ds_read_b128, imm-offset tau*1024
                wh.u = sW[8 + tau][l];
                acc[tau] = __builtin_amdgcn_mfma_f32_16x16x32_f16(xa[m].h, wi.h, acc[tau], 0, 0, 0);
                acc[tau] = __builtin_amdgcn_mfma_f32_16x16x32_f16(ha[m].h, wh.h, acc[tau], 0, 0, 0);
            }
            #pragma unroll
            for (int r = 0; r < 4; ++r) {
                const int lrow = m * 16 + q * 4 + r;      // C row = 4*(l>>4)+reg (m89)
                const float hA = cellh(acc[0][r], acc[2][r], acc[4][r], acc[6][r], c1a[m][r]);
                const float hB = cellh(acc[1][r], acc[3][r], acc[5][r], acc[7][r], c1b[m][r]);
                Hh[lrow * 40 + r16] = (_Float16)hA;                   // j = r16
                if (r16 < 8) Hh[lrow * 40 + 16 + r16] = (_Float16)hB; // j = 16+r16
            }
        }
        __builtin_amdgcn_sched_barrier(0);   // h1 writes before hc reads (RAW)

        // ---- prefetch x(t+1) here: latency hides under L2 + next convert ----
        if (t < T - 1) {
            #pragma unroll
            for (int m = 0; m < 2; ++m) {
                const float* __restrict__ p = (m ? xp1 : xp0) + (t + 1) * NF;
                xr_[m][0] = *reinterpret_cast<const float2*>(p);
                xr_[m][1] = q3 ? z2 : *reinterpret_cast<const float2*>(p + 2);
                xr_[m][2] = q3 ? z2 : *reinterpret_cast<const float2*>(p + 4);
                xr_[m][3] = q3 ? z2 : *reinterpret_cast<const float2*>(p + 6);
            }
        }

        // ---- layer 2: A = [h1(t) | h2(t-1)], 4 MFMA per M-tile ----
        Q hc[2];
        #pragma unroll
        for (int m = 0; m < 2; ++m) hc[m].u = HQ[(m * 16 + r16) * 5 + q];
        __builtin_amdgcn_sched_barrier(0);   // hc reads before h2 overwrite (WAR)
        #pragma unroll
        for (int m = 0; m < 2; ++m) {
            f32x4 a2[4];
            #pragma unroll
            for (int t2 = 0; t2 < 4; ++t2) {
                const float b = bias2[t2];
                f32x4 bv = {b, b, b, b};
                a2[t2] = bv;
            }
            #pragma unroll
            for (int t2 = 0; t2 < 4; ++t2) {
                Q wc; wc.u = sW[16 + t2][l];
                a2[t2] = __builtin_amdgcn_mfma_f32_16x16x32_f16(hc[m].h, wc.h, a2[t2], 0, 0, 0);
            }
            #pragma unroll
            for (int r = 0; r < 4; ++r) {
                const int lrow = m * 16 + q * 4 + r;
                const float h2v = cellh(a2[0][r], a2[1][r], a2[2][r], a2[3][r], c2s[m][r]);
                if (r16 < 8) Hh[lrow * 40 + 24 + r16] = (_Float16)h2v; // h2 cols 24..31
            }
        }
        __builtin_amdgcn_sched_barrier(0);   // h2 writes before next-t ha reads (RAW)
    }

    // ---- epilogue: read final h2 from sH, coalesced float4 out ----
    // lane l -> row erow = l>>1 (0..31), col group ecg = l&1 (cols 4*ecg..4*ecg+3)
    {
        const int erow = l >> 1, ecg = l & 1;
        const uint2 hv = *reinterpret_cast<const uint2*>(&Hh[erow * 40 + 24 + ecg * 4]);
        union { uint u; fp16x2 p; } a0, a1;
        a0.u = hv.x; a1.u = hv.y;
        const int orow = wb + erow;
        if (orow < batch) {
            float4 o = make_float4((float)a0.p[0], (float)a0.p[1],
                                   (float)a1.p[0], (float)a1.p[1]);
            *reinterpret_cast<float4*>(out + (size_t)orow * H2 + ecg * 4) = o;
        }
    }
}

extern "C" void kernel_launch(void* const* d_in, const int* in_sizes, int n_in,
                              void* d_out, int out_size, void* d_ws, size_t ws_size,
                              hipStream_t stream)
{
    const float* x     = (const float*)d_in[0];
    const float* w_ih1 = (const float*)d_in[1];
    const float* w_hh1 = (const float*)d_in[2];
    const float* b_ih1 = (const float*)d_in[3];
    const float* b_hh1 = (const float*)d_in[4];
    const float* w_ih2 = (const float*)d_in[5];
    const float* w_hh2 = (const float*)d_in[6];
    const float* b_ih2 = (const float*)d_in[7];
    const float* b_hh2 = (const float*)d_in[8];
    float* out = (float*)d_out;

    const int batch = in_sizes[0] / (T * NF);
    const int block = 256;                    // 4 waves x 32 batch rows
    const int grid  = (batch + 127) / 128;
    lstm2_mfma<<<grid, block, 0, stream>>>(x, w_ih1, w_hh1, b_ih1, b_hh1,
                                           w_ih2, w_hh2, b_ih2, b_hh2,
                                           out, batch);
}

// Round 12
// 242.661 us; speedup vs baseline: 1.2101x; 1.2101x over previous
//
#include <hip/hip_runtime.h>

#define DEV_INLINE __device__ __forceinline__

constexpr int NF = 26;   // input features
constexpr int H1 = 24;   // layer-1 hidden
constexpr int H2 = 8;    // layer-2 hidden
constexpr int T  = 5;    // sequence length
constexpr int BPW  = 32; // batch rows per wave (2 M-tiles of 16)
constexpr int ROWU = 20; // uints per LDS h-row (40 f16 = 80 B)

typedef _Float16 f16x8 __attribute__((ext_vector_type(8)));
typedef float    f32x4 __attribute__((ext_vector_type(4)));
typedef __fp16   fp16x2 __attribute__((ext_vector_type(2)));

union Q { uint4 u; f16x8 h; };

DEV_INLINE float fast_rcp(float x) { return __builtin_amdgcn_rcpf(x); }
DEV_INLINE float fast_sigmoid(float x) { return fast_rcp(1.0f + __expf(-x)); }
DEV_INLINE float fast_tanh(float x) {
    return fmaf(2.0f, fast_rcp(1.0f + __expf(-2.0f * x)), -1.0f);
}
DEV_INLINE float cellh(float i_, float f_, float g_, float o_, float& c) {
    const float ig = fast_sigmoid(i_), fg = fast_sigmoid(f_);
    const float gg = fast_tanh(g_),    og = fast_sigmoid(o_);
    c = fmaf(fg, c, ig * gg);
    return og * fast_tanh(c);
}
DEV_INLINE uint pkrtz(float a, float b) {
    union { uint u; fp16x2 p; } v; v.p = __builtin_amdgcn_cvt_pkrtz(a, b); return v.u;
}

// R12 = R11 structure with __launch_bounds__(256,3): weight B-fragments in
// block-shared LDS (sW, staged once), sH wave-private [h1|h2] f16 state,
// no __syncthreads in the t-loop. (256,4) in R11 forced a 128-reg cap and
// spilled the recurrent state (WRITE_SIZE 328 MB); (256,3) gives ~170 regs,
// above the ~120-reg live peak -> no spill, 3 waves/SIMD vs R10's 2.

__global__ __launch_bounds__(256, 3) void lstm2_mfma(
    const float* __restrict__ x,
    const float* __restrict__ w_ih1, const float* __restrict__ w_hh1,
    const float* __restrict__ b_ih1, const float* __restrict__ b_hh1,
    const float* __restrict__ w_ih2, const float* __restrict__ w_hh2,
    const float* __restrict__ b_ih2, const float* __restrict__ b_hh2,
    float* __restrict__ out, int batch)
{
    __shared__ uint4 sW[20][64];         // 20 KiB: weight B-fragments, block-shared
    __shared__ uint  sH[4][BPW * ROWU];  // 10 KiB: [h1|h2] f16 state, wave-private

    const int tid = threadIdx.x;
    const int w   = tid >> 6;        // wave id
    const int l   = tid & 63;        // lane
    const int q   = l >> 4;          // quarter (k-slice 8q..8q+7)
    const int r16 = l & 15;          // row (A) / col (B,C) within 16x16 tile
    const int wb  = blockIdx.x * 128 + w * BPW;

    // ---- zero sH (h=0 init); wave-private ----
    for (int i = l; i < BPW * ROWU; i += 64) sH[w][i] = 0u;

    // ---- issue x(t=0) loads early (complete during weight staging) ----
    int row0 = wb + r16;      if (row0 > batch - 1) row0 = batch - 1;
    int row1 = wb + 16 + r16; if (row1 > batch - 1) row1 = batch - 1;
    const float* __restrict__ xp0 = x + (size_t)row0 * (T * NF) + q * 8;
    const float* __restrict__ xp1 = x + (size_t)row1 * (T * NF) + q * 8;
    const bool q3 = (q == 3);
    const float2 z2 = make_float2(0.0f, 0.0f);

    float2 xr_[2][4];
    #pragma unroll
    for (int m = 0; m < 2; ++m) {
        const float* __restrict__ p = m ? xp1 : xp0;
        xr_[m][0] = *reinterpret_cast<const float2*>(p);
        xr_[m][1] = q3 ? z2 : *reinterpret_cast<const float2*>(p + 2);
        xr_[m][2] = q3 ? z2 : *reinterpret_cast<const float2*>(p + 4);
        xr_[m][3] = q3 ? z2 : *reinterpret_cast<const float2*>(p + 6);
    }

    // ---- cooperative weight staging: wave w does tiles w, w+4, ... ----
    for (int tile = w; tile < 20; tile += 4) {
        f16x8 bf;
        if (tile < 16) {
            const int tau  = tile & 7;
            const int gate = tau >> 1, j = (tau & 1) * 16 + r16;
            const bool jv  = (j < H1);
            const int row  = gate * H1 + (jv ? j : 0);
            const bool ih  = (tile < 8);
            #pragma unroll
            for (int e = 0; e < 8; ++e) {
                const int k = q * 8 + e;
                float v = 0.0f;
                if (ih) { if (jv && k < NF) v = w_ih1[row * NF + k]; }
                else    { if (jv && k < H1) v = w_hh1[row * H1 + k]; }
                bf[e] = (_Float16)v;
            }
        } else {
            const int t2  = tile - 16;
            const bool jv = (r16 < H2);
            const int row = t2 * H2 + (jv ? r16 : 0);
            #pragma unroll
            for (int e = 0; e < 8; ++e) {
                const int k = q * 8 + e;
                float v = 0.0f;
                if (jv) v = (k < H1) ? w_ih2[row * H1 + k] : w_hh2[row * H2 + (k - H1)];
                bf[e] = (_Float16)v;
            }
        }
        Q u; u.h = bf;
        sW[tile][l] = u.u;
    }

    // ---- biases in regs (12 scalars, per-lane) ----
    float bias1[8], bias2[4];
    #pragma unroll
    for (int tau = 0; tau < 8; ++tau) {
        const int gate = tau >> 1, j = (tau & 1) * 16 + r16;
        const bool jv  = (j < H1);
        const int row  = gate * H1 + (jv ? j : 0);
        bias1[tau] = jv ? (b_ih1[row] + b_hh1[row]) : 0.0f;
    }
    #pragma unroll
    for (int t2 = 0; t2 < 4; ++t2) {
        const bool jv = (r16 < H2);
        const int row = t2 * H2 + (jv ? r16 : 0);
        bias2[t2] = jv ? (b_ih2[row] + b_hh2[row]) : 0.0f;
    }

    __syncthreads();   // weights visible to all waves (only barrier in kernel)

    float c1a[2][4] = {}, c1b[2][4] = {}, c2s[2][4] = {};
    const uint4* HQ = reinterpret_cast<const uint4*>(&sH[w][0]);
    _Float16*   Hh  = reinterpret_cast<_Float16*>(&sH[w][0]);

    #pragma unroll 1
    for (int t = 0; t < T; ++t) {
        // ---- convert raw x -> A-frags ----
        Q xa[2];
        #pragma unroll
        for (int m = 0; m < 2; ++m) {
            uint4 u;
            u.x = pkrtz(xr_[m][0].x, xr_[m][0].y);
            u.y = pkrtz(xr_[m][1].x, xr_[m][1].y);
            u.z = pkrtz(xr_[m][2].x, xr_[m][2].y);
            u.w = pkrtz(xr_[m][3].x, xr_[m][3].y);
            xa[m].u = u;
        }

        // ---- read [h1|h2](prev t) A-frags ----
        Q ha[2];
        #pragma unroll
        for (int m = 0; m < 2; ++m) ha[m].u = HQ[(m * 16 + r16) * 5 + q];
        __builtin_amdgcn_sched_barrier(0);   // frag reads before h1 overwrite (WAR)

        // ---- layer 1: weights from LDS, 16 MFMA per M-tile, cells ----
        #pragma unroll
        for (int m = 0; m < 2; ++m) {
            f32x4 acc[8];
            #pragma unroll
            for (int tau = 0; tau < 8; ++tau) {
                const float b = bias1[tau];
                f32x4 bv = {b, b, b, b};
                acc[tau] = bv;
            }
            #pragma unroll
            for (int tau = 0; tau < 8; ++tau) {
                Q wi, wh;
                wi.u = sW[tau][l];          // ds_read_b128, imm-offset tau*1024
                wh.u = sW[8 + tau][l];
                acc[tau] = __builtin_amdgcn_mfma_f32_16x16x32_f16(xa[m].h, wi.h, acc[tau], 0, 0, 0);
                acc[tau] = __builtin_amdgcn_mfma_f32_16x16x32_f16(ha[m].h, wh.h, acc[tau], 0, 0, 0);
            }
            #pragma unroll
            for (int r = 0; r < 4; ++r) {
                const int lrow = m * 16 + q * 4 + r;      // C row = 4*(l>>4)+reg (m89)
                const float hA = cellh(acc[0][r], acc[2][r], acc[4][r], acc[6][r], c1a[m][r]);
                const float hB = cellh(acc[1][r], acc[3][r], acc[5][r], acc[7][r], c1b[m][r]);
                Hh[lrow * 40 + r16] = (_Float16)hA;                   // j = r16
                if (r16 < 8) Hh[lrow * 40 + 16 + r16] = (_Float16)hB; // j = 16+r16
            }
        }
        __builtin_amdgcn_sched_barrier(0);   // h1 writes before hc reads (RAW)

        // ---- prefetch x(t+1) here: latency hides under L2 + next convert ----
        if (t < T - 1) {
            #pragma unroll
            for (int m = 0; m < 2; ++m) {
                const float* __restrict__ p = (m ? xp1 : xp0) + (t + 1) * NF;
                xr_[m][0] = *reinterpret_cast<const float2*>(p);
                xr_[m][1] = q3 ? z2 : *reinterpret_cast<const float2*>(p + 2);
                xr_[m][2] = q3 ? z2 : *reinterpret_cast<const float2*>(p + 4);
                xr_[m][3] = q3 ? z2 : *reinterpret_cast<const float2*>(p + 6);
            }
        }

        // ---- layer 2: A = [h1(t) | h2(t-1)], 4 MFMA per M-tile ----
        Q hc[2];
        #pragma unroll
        for (int m = 0; m < 2; ++m) hc[m].u = HQ[(m * 16 + r16) * 5 + q];
        __builtin_amdgcn_sched_barrier(0);   // hc reads before h2 overwrite (WAR)
        #pragma unroll
        for (int m = 0; m < 2; ++m) {
            f32x4 a2[4];
            #pragma unroll
            for (int t2 = 0; t2 < 4; ++t2) {
                const float b = bias2[t2];
                f32x4 bv = {b, b, b, b};
                a2[t2] = bv;
            }
            #pragma unroll
            for (int t2 = 0; t2 < 4; ++t2) {
                Q wc; wc.u = sW[16 + t2][l];
                a2[t2] = __builtin_amdgcn_mfma_f32_16x16x32_f16(hc[m].h, wc.h, a2[t2], 0, 0, 0);
            }
            #pragma unroll
            for (int r = 0; r < 4; ++r) {
                const int lrow = m * 16 + q * 4 + r;
                const float h2v = cellh(a2[0][r], a2[1][r], a2[2][r], a2[3][r], c2s[m][r]);
                if (r16 < 8) Hh[lrow * 40 + 24 + r16] = (_Float16)h2v; // h2 cols 24..31
            }
        }
        __builtin_amdgcn_sched_barrier(0);   // h2 writes before next-t ha reads (RAW)
    }

    // ---- epilogue: read final h2 from sH, coalesced float4 out ----
    // lane l -> row erow = l>>1 (0..31), col group ecg = l&1 (cols 4*ecg..4*ecg+3)
    {
        const int erow = l >> 1, ecg = l & 1;
        const uint2 hv = *reinterpret_cast<const uint2*>(&Hh[erow * 40 + 24 + ecg * 4]);
        union { uint u; fp16x2 p; } a0, a1;
        a0.u = hv.x; a1.u = hv.y;
        const int orow = wb + erow;
        if (orow < batch) {
            float4 o = make_float4((float)a0.p[0], (float)a0.p[1],
                                   (float)a1.p[0], (float)a1.p[1]);
            *reinterpret_cast<float4*>(out + (size_t)orow * H2 + ecg * 4) = o;
        }
    }
}

extern "C" void kernel_launch(void* const* d_in, const int* in_sizes, int n_in,
                              void* d_out, int out_size, void* d_ws, size_t ws_size,
                              hipStream_t stream)
{
    const float* x     = (const float*)d_in[0];
    const float* w_ih1 = (const float*)d_in[1];
    const float* w_hh1 = (const float*)d_in[2];
    const float* b_ih1 = (const float*)d_in[3];
    const float* b_hh1 = (const float*)d_in[4];
    const float* w_ih2 = (const float*)d_in[5];
    const float* w_hh2 = (const float*)d_in[6];
    const float* b_ih2 = (const float*)d_in[7];
    const float* b_hh2 = (const float*)d_in[8];
    float* out = (float*)d_out;

    const int batch = in_sizes[0] / (T * NF);
    const int block = 256;                    // 4 waves x 32 batch rows
    const int grid  = (batch + 127) / 128;
    lstm2_mfma<<<grid, block, 0, stream>>>(x, w_ih1, w_hh1, b_ih1, b_hh1,
                                           w_ih2, w_hh2, b_ih2, b_hh2,
                                           out, batch);
}

// Round 13
// 115.423 us; speedup vs baseline: 2.5440x; 2.1024x over previous
//
#include <hip/hip_runtime.h>

#define DEV_INLINE __device__ __forceinline__

constexpr int NF = 26;   // input features
constexpr int H1 = 24;   // layer-1 hidden
constexpr int H2 = 8;    // layer-2 hidden
constexpr int T  = 5;    // sequence length
constexpr int BPW  = 32; // batch rows per wave (2 M-tiles of 16)
constexpr int ROWU = 20; // uints per LDS h-row (40 f16 = 80 B)

typedef _Float16 f16x8 __attribute__((ext_vector_type(8)));
typedef float    f32x4 __attribute__((ext_vector_type(4)));
typedef __fp16   fp16x2 __attribute__((ext_vector_type(2)));

union Q { uint4 u; f16x8 h; };

DEV_INLINE float fast_rcp(float x) { return __builtin_amdgcn_rcpf(x); }
DEV_INLINE float fast_sigmoid(float x) { return fast_rcp(1.0f + __expf(-x)); }
DEV_INLINE float fast_tanh(float x) {
    return fmaf(2.0f, fast_rcp(1.0f + __expf(-2.0f * x)), -1.0f);
}
DEV_INLINE float cellh(float i_, float f_, float g_, float o_, float& c) {
    const float ig = fast_sigmoid(i_), fg = fast_sigmoid(f_);
    const float gg = fast_tanh(g_),    og = fast_sigmoid(o_);
    c = fmaf(fg, c, ig * gg);
    return og * fast_tanh(c);
}
DEV_INLINE uint pkrtz(float a, float b) {
    union { uint u; fp16x2 p; } v; v.p = __builtin_amdgcn_cvt_pkrtz(a, b); return v.u;
}

// R13 = R12 with the register-pressure causes removed:
//  * weight fragment read ONCE per t, feeds BOTH M-tiles (acc[2][8] fixed 64-AGPR
//    live set instead of scheduler-hoisted 32 ds_reads -> spill in R11/R12)
//  * sched_barrier(0) per tau-pair caps the in-flight fragment window at 16 regs
//  * x loaded JIT per t (no 16-reg persistent prefetch); L2-hit after t=0
// sW block-shared (staged once), sH wave-private, no __syncthreads in t-loop.

__global__ __launch_bounds__(256, 3) void lstm2_mfma(
    const float* __restrict__ x,
    const float* __restrict__ w_ih1, const float* __restrict__ w_hh1,
    const float* __restrict__ b_ih1, const float* __restrict__ b_hh1,
    const float* __restrict__ w_ih2, const float* __restrict__ w_hh2,
    const float* __restrict__ b_ih2, const float* __restrict__ b_hh2,
    float* __restrict__ out, int batch)
{
    __shared__ uint4 sW[20][64];         // 20 KiB: weight B-fragments, block-shared
    __shared__ uint  sH[4][BPW * ROWU];  // 10 KiB: [h1|h2] f16 state, wave-private

    const int tid = threadIdx.x;
    const int w   = tid >> 6;        // wave id
    const int l   = tid & 63;        // lane
    const int q   = l >> 4;          // quarter (k-slice 8q..8q+7)
    const int r16 = l & 15;          // row (A) / col (B,C) within 16x16 tile
    const int wb  = blockIdx.x * 128 + w * BPW;

    // ---- zero sH (h=0 init); wave-private ----
    for (int i = l; i < BPW * ROWU; i += 64) sH[w][i] = 0u;

    // ---- x pointers (clamped rows) ----
    int row0 = wb + r16;      if (row0 > batch - 1) row0 = batch - 1;
    int row1 = wb + 16 + r16; if (row1 > batch - 1) row1 = batch - 1;
    const float* __restrict__ xp0 = x + (size_t)row0 * (T * NF) + q * 8;
    const float* __restrict__ xp1 = x + (size_t)row1 * (T * NF) + q * 8;
    const bool q3 = (q == 3);
    const float2 z2 = make_float2(0.0f, 0.0f);

    // ---- cooperative weight staging: wave w does tiles w, w+4, ... ----
    for (int tile = w; tile < 20; tile += 4) {
        f16x8 bf;
        if (tile < 16) {
            const int tau  = tile & 7;
            const int gate = tau >> 1, j = (tau & 1) * 16 + r16;
            const bool jv  = (j < H1);
            const int row  = gate * H1 + (jv ? j : 0);
            const bool ih  = (tile < 8);
            #pragma unroll
            for (int e = 0; e < 8; ++e) {
                const int k = q * 8 + e;
                float v = 0.0f;
                if (ih) { if (jv && k < NF) v = w_ih1[row * NF + k]; }
                else    { if (jv && k < H1) v = w_hh1[row * H1 + k]; }
                bf[e] = (_Float16)v;
            }
        } else {
            const int t2  = tile - 16;
            const bool jv = (r16 < H2);
            const int row = t2 * H2 + (jv ? r16 : 0);
            #pragma unroll
            for (int e = 0; e < 8; ++e) {
                const int k = q * 8 + e;
                float v = 0.0f;
                if (jv) v = (k < H1) ? w_ih2[row * H1 + k] : w_hh2[row * H2 + (k - H1)];
                bf[e] = (_Float16)v;
            }
        }
        Q u; u.h = bf;
        sW[tile][l] = u.u;
    }

    // ---- biases in regs (12 scalars, per-lane) ----
    float bias1[8], bias2[4];
    #pragma unroll
    for (int tau = 0; tau < 8; ++tau) {
        const int gate = tau >> 1, j = (tau & 1) * 16 + r16;
        const bool jv  = (j < H1);
        const int row  = gate * H1 + (jv ? j : 0);
        bias1[tau] = jv ? (b_ih1[row] + b_hh1[row]) : 0.0f;
    }
    #pragma unroll
    for (int t2 = 0; t2 < 4; ++t2) {
        const bool jv = (r16 < H2);
        const int row = t2 * H2 + (jv ? r16 : 0);
        bias2[t2] = jv ? (b_ih2[row] + b_hh2[row]) : 0.0f;
    }

    __syncthreads();   // weights visible to all waves (only barrier in kernel)

    float c1a[2][4] = {}, c1b[2][4] = {}, c2s[2][4] = {};
    const uint4* HQ = reinterpret_cast<const uint4*>(&sH[w][0]);
    _Float16*   Hh  = reinterpret_cast<_Float16*>(&sH[w][0]);

    #pragma unroll 1
    for (int t = 0; t < T; ++t) {
        // ---- JIT x load + convert (no persistent prefetch regs) ----
        Q xa[2];
        #pragma unroll
        for (int m = 0; m < 2; ++m) {
            const float* __restrict__ p = (m ? xp1 : xp0) + t * NF;
            float2 v0 = *reinterpret_cast<const float2*>(p);
            float2 v1 = q3 ? z2 : *reinterpret_cast<const float2*>(p + 2);
            float2 v2 = q3 ? z2 : *reinterpret_cast<const float2*>(p + 4);
            float2 v3 = q3 ? z2 : *reinterpret_cast<const float2*>(p + 6);
            uint4 u;
            u.x = pkrtz(v0.x, v0.y);
            u.y = pkrtz(v1.x, v1.y);
            u.z = pkrtz(v2.x, v2.y);
            u.w = pkrtz(v3.x, v3.y);
            xa[m].u = u;
        }

        // ---- read [h1|h2](prev t) A-frags ----
        Q ha[2];
        #pragma unroll
        for (int m = 0; m < 2; ++m) ha[m].u = HQ[(m * 16 + r16) * 5 + q];
        __builtin_amdgcn_sched_barrier(0);   // frag reads before h1 overwrite (WAR)

        // ---- layer 1: each weight fragment read once, feeds both M-tiles ----
        f32x4 acc[2][8];
        #pragma unroll
        for (int tau = 0; tau < 8; ++tau) {
            const float b = bias1[tau];
            f32x4 bv = {b, b, b, b};
            acc[0][tau] = bv;
            acc[1][tau] = bv;
        }
        #pragma unroll
        for (int tp = 0; tp < 4; ++tp) {
            #pragma unroll
            for (int ti = 0; ti < 2; ++ti) {
                const int tau = 2 * tp + ti;
                Q wi, wh;
                wi.u = sW[tau][l];          // one ds_read_b128 each, imm offsets
                wh.u = sW[8 + tau][l];
                acc[0][tau] = __builtin_amdgcn_mfma_f32_16x16x32_f16(xa[0].h, wi.h, acc[0][tau], 0, 0, 0);
                acc[1][tau] = __builtin_amdgcn_mfma_f32_16x16x32_f16(xa[1].h, wi.h, acc[1][tau], 0, 0, 0);
                acc[0][tau] = __builtin_amdgcn_mfma_f32_16x16x32_f16(ha[0].h, wh.h, acc[0][tau], 0, 0, 0);
                acc[1][tau] = __builtin_amdgcn_mfma_f32_16x16x32_f16(ha[1].h, wh.h, acc[1][tau], 0, 0, 0);
            }
            __builtin_amdgcn_sched_barrier(0);   // cap in-flight frags at 4 (16 regs)
        }
        #pragma unroll
        for (int m = 0; m < 2; ++m) {
            #pragma unroll
            for (int r = 0; r < 4; ++r) {
                const int lrow = m * 16 + q * 4 + r;      // C row = 4*(l>>4)+reg (m89)
                const float hA = cellh(acc[m][0][r], acc[m][2][r], acc[m][4][r], acc[m][6][r], c1a[m][r]);
                const float hB = cellh(acc[m][1][r], acc[m][3][r], acc[m][5][r], acc[m][7][r], c1b[m][r]);
                Hh[lrow * 40 + r16] = (_Float16)hA;                   // j = r16
                if (r16 < 8) Hh[lrow * 40 + 16 + r16] = (_Float16)hB; // j = 16+r16
            }
        }
        __builtin_amdgcn_sched_barrier(0);   // h1 writes before hc reads (RAW)

        // ---- layer 2: A = [h1(t) | h2(t-1)], weights read once ----
        Q hc[2];
        #pragma unroll
        for (int m = 0; m < 2; ++m) hc[m].u = HQ[(m * 16 + r16) * 5 + q];
        __builtin_amdgcn_sched_barrier(0);   // hc reads before h2 overwrite (WAR)
        f32x4 a2[2][4];
        #pragma unroll
        for (int t2 = 0; t2 < 4; ++t2) {
            const float b = bias2[t2];
            f32x4 bv = {b, b, b, b};
            a2[0][t2] = bv;
            a2[1][t2] = bv;
        }
        #pragma unroll
        for (int t2 = 0; t2 < 4; ++t2) {
            Q wc; wc.u = sW[16 + t2][l];
            a2[0][t2] = __builtin_amdgcn_mfma_f32_16x16x32_f16(hc[0].h, wc.h, a2[0][t2], 0, 0, 0);
            a2[1][t2] = __builtin_amdgcn_mfma_f32_16x16x32_f16(hc[1].h, wc.h, a2[1][t2], 0, 0, 0);
        }
        __builtin_amdgcn_sched_barrier(0);
        #pragma unroll
        for (int m = 0; m < 2; ++m) {
            #pragma unroll
            for (int r = 0; r < 4; ++r) {
                const int lrow = m * 16 + q * 4 + r;
                const float h2v = cellh(a2[m][0][r], a2[m][1][r], a2[m][2][r], a2[m][3][r], c2s[m][r]);
                if (r16 < 8) Hh[lrow * 40 + 24 + r16] = (_Float16)h2v; // h2 cols 24..31
            }
        }
        __builtin_amdgcn_sched_barrier(0);   // h2 writes before next-t ha reads (RAW)
    }

    // ---- epilogue: read final h2 from sH, coalesced float4 out ----
    {
        const int erow = l >> 1, ecg = l & 1;
        const uint2 hv = *reinterpret_cast<const uint2*>(&Hh[erow * 40 + 24 + ecg * 4]);
        union { uint u; fp16x2 p; } a0, a1;
        a0.u = hv.x; a1.u = hv.y;
        const int orow = wb + erow;
        if (orow < batch) {
            float4 o = make_float4((float)a0.p[0], (float)a0.p[1],
                                   (float)a1.p[0], (float)a1.p[1]);
            *reinterpret_cast<float4*>(out + (size_t)orow * H2 + ecg * 4) = o;
        }
    }
}

extern "C" void kernel_launch(void* const* d_in, const int* in_sizes, int n_in,
                              void* d_out, int out_size, void* d_ws, size_t ws_size,
                              hipStream_t stream)
{
    const float* x     = (const float*)d_in[0];
    const float* w_ih1 = (const float*)d_in[1];
    const float* w_hh1 = (const float*)d_in[2];
    const float* b_ih1 = (const float*)d_in[3];
    const float* b_hh1 = (const float*)d_in[4];
    const float* w_ih2 = (const float*)d_in[5];
    const float* w_hh2 = (const float*)d_in[6];
    const float* b_ih2 = (const float*)d_in[7];
    const float* b_hh2 = (const float*)d_in[8];
    float* out = (float*)d_out;

    const int batch = in_sizes[0] / (T * NF);
    const int block = 256;                    // 4 waves x 32 batch rows
    const int grid  = (batch + 127) / 128;
    lstm2_mfma<<<grid, block, 0, stream>>>(x, w_ih1, w_hh1, b_ih1, b_hh1,
                                           w_ih2, w_hh2, b_ih2, b_hh2,
                                           out, batch);
}

// Round 14
// 111.100 us; speedup vs baseline: 2.6430x; 1.0389x over previous
//
#include <hip/hip_runtime.h>

#define DEV_INLINE __device__ __forceinline__

constexpr int NF = 26;   // input features
constexpr int H1 = 24;   // layer-1 hidden
constexpr int H2 = 8;    // layer-2 hidden
constexpr int T  = 5;    // sequence length
constexpr int BPW  = 32; // batch rows per wave (2 M-tiles of 16)
constexpr int ROWU = 20; // uints per LDS h-row (40 f16 = 80 B)

typedef _Float16 f16x8 __attribute__((ext_vector_type(8)));
typedef float    f32x4 __attribute__((ext_vector_type(4)));
typedef __fp16   fp16x2 __attribute__((ext_vector_type(2)));

union Q { uint4 u; f16x8 h; };

DEV_INLINE float fast_rcp(float x) { return __builtin_amdgcn_rcpf(x); }
DEV_INLINE float fast_sigmoid(float x) { return fast_rcp(1.0f + __expf(-x)); }
DEV_INLINE float fast_tanh(float x) {
    return fmaf(2.0f, fast_rcp(1.0f + __expf(-2.0f * x)), -1.0f);
}
DEV_INLINE float cellh(float i_, float f_, float g_, float o_, float& c) {
    const float ig = fast_sigmoid(i_), fg = fast_sigmoid(f_);
    const float gg = fast_tanh(g_),    og = fast_sigmoid(o_);
    c = fmaf(fg, c, ig * gg);
    return og * fast_tanh(c);
}
DEV_INLINE uint pkrtz(float a, float b) {
    union { uint u; fp16x2 p; } v; v.p = __builtin_amdgcn_cvt_pkrtz(a, b); return v.u;
}

// R14 = R13 with layer-1 split by gate-parity so the accumulator live set is
// acc[2][4] (32 regs) per half instead of acc[2][8] (64): even taus compute the
// 4 gates of j=r16 (-> cells -> Hh col r16), odd taus the 4 gates of j=16+r16.
// Every weight fragment is still read exactly once per t. Peak live ~125 regs
// -> __launch_bounds__(256,4): 4 waves/SIMD (R11's spill was the 190-reg
// scheduler set; R13 bounded it to ~150; this bounds it to ~125).
// sW block-shared (staged once), sH wave-private, no __syncthreads in t-loop.

__global__ __launch_bounds__(256, 4) void lstm2_mfma(
    const float* __restrict__ x,
    const float* __restrict__ w_ih1, const float* __restrict__ w_hh1,
    const float* __restrict__ b_ih1, const float* __restrict__ b_hh1,
    const float* __restrict__ w_ih2, const float* __restrict__ w_hh2,
    const float* __restrict__ b_ih2, const float* __restrict__ b_hh2,
    float* __restrict__ out, int batch)
{
    __shared__ uint4 sW[20][64];         // 20 KiB: weight B-fragments, block-shared
    __shared__ uint  sH[4][BPW * ROWU];  // 10 KiB: [h1|h2] f16 state, wave-private

    const int tid = threadIdx.x;
    const int w   = tid >> 6;        // wave id
    const int l   = tid & 63;        // lane
    const int q   = l >> 4;          // quarter (k-slice 8q..8q+7)
    const int r16 = l & 15;          // row (A) / col (B,C) within 16x16 tile
    const int wb  = blockIdx.x * 128 + w * BPW;

    // ---- zero sH (h=0 init); wave-private ----
    for (int i = l; i < BPW * ROWU; i += 64) sH[w][i] = 0u;

    // ---- x pointers (clamped rows) ----
    int row0 = wb + r16;      if (row0 > batch - 1) row0 = batch - 1;
    int row1 = wb + 16 + r16; if (row1 > batch - 1) row1 = batch - 1;
    const float* __restrict__ xp0 = x + (size_t)row0 * (T * NF) + q * 8;
    const float* __restrict__ xp1 = x + (size_t)row1 * (T * NF) + q * 8;
    const bool q3 = (q == 3);
    const float2 z2 = make_float2(0.0f, 0.0f);

    // ---- cooperative weight staging: wave w does tiles w, w+4, ... ----
    for (int tile = w; tile < 20; tile += 4) {
        f16x8 bf;
        if (tile < 16) {
            const int tau  = tile & 7;
            const int gate = tau >> 1, j = (tau & 1) * 16 + r16;
            const bool jv  = (j < H1);
            const int row  = gate * H1 + (jv ? j : 0);
            const bool ih  = (tile < 8);
            #pragma unroll
            for (int e = 0; e < 8; ++e) {
                const int k = q * 8 + e;
                float v = 0.0f;
                if (ih) { if (jv && k < NF) v = w_ih1[row * NF + k]; }
                else    { if (jv && k < H1) v = w_hh1[row * H1 + k]; }
                bf[e] = (_Float16)v;
            }
        } else {
            const int t2  = tile - 16;
            const bool jv = (r16 < H2);
            const int row = t2 * H2 + (jv ? r16 : 0);
            #pragma unroll
            for (int e = 0; e < 8; ++e) {
                const int k = q * 8 + e;
                float v = 0.0f;
                if (jv) v = (k < H1) ? w_ih2[row * H1 + k] : w_hh2[row * H2 + (k - H1)];
                bf[e] = (_Float16)v;
            }
        }
        Q u; u.h = bf;
        sW[tile][l] = u.u;
    }

    // ---- biases in regs (12 scalars, per-lane) ----
    float bias1[8], bias2[4];
    #pragma unroll
    for (int tau = 0; tau < 8; ++tau) {
        const int gate = tau >> 1, j = (tau & 1) * 16 + r16;
        const bool jv  = (j < H1);
        const int row  = gate * H1 + (jv ? j : 0);
        bias1[tau] = jv ? (b_ih1[row] + b_hh1[row]) : 0.0f;
    }
    #pragma unroll
    for (int t2 = 0; t2 < 4; ++t2) {
        const bool jv = (r16 < H2);
        const int row = t2 * H2 + (jv ? r16 : 0);
        bias2[t2] = jv ? (b_ih2[row] + b_hh2[row]) : 0.0f;
    }

    __syncthreads();   // weights visible to all waves (only barrier in kernel)

    float c1a[2][4] = {}, c1b[2][4] = {}, c2s[2][4] = {};
    const uint4* HQ = reinterpret_cast<const uint4*>(&sH[w][0]);
    _Float16*   Hh  = reinterpret_cast<_Float16*>(&sH[w][0]);

    #pragma unroll 1
    for (int t = 0; t < T; ++t) {
        // ---- JIT x load + convert ----
        Q xa[2];
        #pragma unroll
        for (int m = 0; m < 2; ++m) {
            const float* __restrict__ p = (m ? xp1 : xp0) + t * NF;
            float2 v0 = *reinterpret_cast<const float2*>(p);
            float2 v1 = q3 ? z2 : *reinterpret_cast<const float2*>(p + 2);
            float2 v2 = q3 ? z2 : *reinterpret_cast<const float2*>(p + 4);
            float2 v3 = q3 ? z2 : *reinterpret_cast<const float2*>(p + 6);
            uint4 u;
            u.x = pkrtz(v0.x, v0.y);
            u.y = pkrtz(v1.x, v1.y);
            u.z = pkrtz(v2.x, v2.y);
            u.w = pkrtz(v3.x, v3.y);
            xa[m].u = u;
        }

        // ---- read [h1|h2](prev t) A-frags ----
        Q ha[2];
        #pragma unroll
        for (int m = 0; m < 2; ++m) ha[m].u = HQ[(m * 16 + r16) * 5 + q];
        __builtin_amdgcn_sched_barrier(0);   // frag reads before h1 overwrite (WAR)

        // ---- layer 1 in two gate-parity halves (32-reg acc each) ----
        #pragma unroll
        for (int h = 0; h < 2; ++h) {        // h=0: j=r16 ; h=1: j=16+r16
            f32x4 acc[2][4];
            #pragma unroll
            for (int g = 0; g < 4; ++g) {
                const float b = bias1[2 * g + h];
                f32x4 bv = {b, b, b, b};
                acc[0][g] = bv;
                acc[1][g] = bv;
            }
            #pragma unroll
            for (int g = 0; g < 4; ++g) {
                const int tau = 2 * g + h;
                Q wi, wh;
                wi.u = sW[tau][l];          // each fragment read once per t
                wh.u = sW[8 + tau][l];
                acc[0][g] = __builtin_amdgcn_mfma_f32_16x16x32_f16(xa[0].h, wi.h, acc[0][g], 0, 0, 0);
                acc[1][g] = __builtin_amdgcn_mfma_f32_16x16x32_f16(xa[1].h, wi.h, acc[1][g], 0, 0, 0);
                acc[0][g] = __builtin_amdgcn_mfma_f32_16x16x32_f16(ha[0].h, wh.h, acc[0][g], 0, 0, 0);
                acc[1][g] = __builtin_amdgcn_mfma_f32_16x16x32_f16(ha[1].h, wh.h, acc[1][g], 0, 0, 0);
                if (g == 1) __builtin_amdgcn_sched_barrier(0);  // cap frag window
            }
            __builtin_amdgcn_sched_barrier(0);
            #pragma unroll
            for (int m = 0; m < 2; ++m) {
                #pragma unroll
                for (int r = 0; r < 4; ++r) {
                    const int lrow = m * 16 + q * 4 + r;  // C row = 4*(l>>4)+reg (m89)
                    float& cref = (h == 0) ? c1a[m][r] : c1b[m][r];
                    const float hv = cellh(acc[m][0][r], acc[m][1][r], acc[m][2][r], acc[m][3][r], cref);
                    if (h == 0) Hh[lrow * 40 + r16] = (_Float16)hv;
                    else if (r16 < 8) Hh[lrow * 40 + 16 + r16] = (_Float16)hv;
                }
            }
            __builtin_amdgcn_sched_barrier(0);
        }

        // ---- layer 2: A = [h1(t) | h2(t-1)], weights read once ----
        Q hc[2];
        #pragma unroll
        for (int m = 0; m < 2; ++m) hc[m].u = HQ[(m * 16 + r16) * 5 + q];
        __builtin_amdgcn_sched_barrier(0);   // hc reads before h2 overwrite (WAR)
        f32x4 a2[2][4];
        #pragma unroll
        for (int t2 = 0; t2 < 4; ++t2) {
            const float b = bias2[t2];
            f32x4 bv = {b, b, b, b};
            a2[0][t2] = bv;
            a2[1][t2] = bv;
        }
        #pragma unroll
        for (int t2 = 0; t2 < 4; ++t2) {
            Q wc; wc.u = sW[16 + t2][l];
            a2[0][t2] = __builtin_amdgcn_mfma_f32_16x16x32_f16(hc[0].h, wc.h, a2[0][t2], 0, 0, 0);
            a2[1][t2] = __builtin_amdgcn_mfma_f32_16x16x32_f16(hc[1].h, wc.h, a2[1][t2], 0, 0, 0);
        }
        __builtin_amdgcn_sched_barrier(0);
        #pragma unroll
        for (int m = 0; m < 2; ++m) {
            #pragma unroll
            for (int r = 0; r < 4; ++r) {
                const int lrow = m * 16 + q * 4 + r;
                const float h2v = cellh(a2[m][0][r], a2[m][1][r], a2[m][2][r], a2[m][3][r], c2s[m][r]);
                if (r16 < 8) Hh[lrow * 40 + 24 + r16] = (_Float16)h2v; // h2 cols 24..31
            }
        }
        __builtin_amdgcn_sched_barrier(0);   // h2 writes before next-t ha reads (RAW)
    }

    // ---- epilogue: read final h2 from sH, coalesced float4 out ----
    {
        const int erow = l >> 1, ecg = l & 1;
        const uint2 hv = *reinterpret_cast<const uint2*>(&Hh[erow * 40 + 24 + ecg * 4]);
        union { uint u; fp16x2 p; } a0, a1;
        a0.u = hv.x; a1.u = hv.y;
        const int orow = wb + erow;
        if (orow < batch) {
            float4 o = make_float4((float)a0.p[0], (float)a0.p[1],
                                   (float)a1.p[0], (float)a1.p[1]);
            *reinterpret_cast<float4*>(out + (size_t)orow * H2 + ecg * 4) = o;
        }
    }
}

extern "C" void kernel_launch(void* const* d_in, const int* in_sizes, int n_in,
                              void* d_out, int out_size, void* d_ws, size_t ws_size,
                              hipStream_t stream)
{
    const float* x     = (const float*)d_in[0];
    const float* w_ih1 = (const float*)d_in[1];
    const float* w_hh1 = (const float*)d_in[2];
    const float* b_ih1 = (const float*)d_in[3];
    const float* b_hh1 = (const float*)d_in[4];
    const float* w_ih2 = (const float*)d_in[5];
    const float* w_hh2 = (const float*)d_in[6];
    const float* b_ih2 = (const float*)d_in[7];
    const float* b_hh2 = (const float*)d_in[8];
    float* out = (float*)d_out;

    const int batch = in_sizes[0] / (T * NF);
    const int block = 256;                    // 4 waves x 32 batch rows
    const int grid  = (batch + 127) / 128;
    lstm2_mfma<<<grid, block, 0, stream>>>(x, w_ih1, w_hh1, b_ih1, b_hh1,
                                           w_ih2, w_hh2, b_ih2, b_hh2,
                                           out, batch);
}

// Round 15
// 85.419 us; speedup vs baseline: 3.4377x; 1.3006x over previous
//
#include <hip/hip_runtime.h>

#define DEV_INLINE __device__ __forceinline__

constexpr int NF = 26;   // input features
constexpr int H1 = 24;   // layer-1 hidden
constexpr int H2 = 8;    // layer-2 hidden
constexpr int T  = 5;    // sequence length
constexpr int BPW  = 32; // batch rows per wave (2 M-tiles of 16)
constexpr int ROWU = 20; // uints per LDS h-row (40 f16 = 80 B)

constexpr float L2E     = 1.44269504088896f;   // log2(e)
constexpr float TWO_L2E = 2.88539008177792f;   // 2*log2(e)

typedef _Float16 f16x8 __attribute__((ext_vector_type(8)));
typedef float    f32x4 __attribute__((ext_vector_type(4)));
typedef __fp16   fp16x2 __attribute__((ext_vector_type(2)));

union Q { uint4 u; f16x8 h; };

DEV_INLINE float fast_rcp(float x) { return __builtin_amdgcn_rcpf(x); }
// 1/(1+2^-x); with pre-scaled gate a = log2e*raw this IS sigmoid(raw).
DEV_INLINE float rcp1p(float x) { return fast_rcp(1.0f + __builtin_amdgcn_exp2f(-x)); }
// cell with PRE-SCALED gates: i,f,o scaled by log2e; g scaled by 2*log2e.
DEV_INLINE float cellp(float i_, float f_, float g_, float o_, float& c) {
    const float ig = rcp1p(i_), fg = rcp1p(f_);
    const float gg = fmaf(2.0f, rcp1p(g_), -1.0f);   // tanh(raw g)
    const float og = rcp1p(o_);
    c = fmaf(fg, c, ig * gg);
    return og * fmaf(2.0f, rcp1p(c * TWO_L2E), -1.0f);   // o*tanh(c)
}
DEV_INLINE uint pkrtz(float a, float b) {
    union { uint u; fp16x2 p; } v; v.p = __builtin_amdgcn_cvt_pkrtz(a, b); return v.u;
}

// R15 = R14 + three pressure/issue cuts:
//  * log2e folded into staged weights+biases (g gate x2log2e): sigmoid/tanh use
//    exp2 directly (v_exp_f32 with folded neg modifier) -> 4 fewer VALU/cell
//  * biases in LDS (sB1/sB2), read per use -> 12 persistent regs freed
//  * ONE acc[2][4] (32 regs) reused by both L1 gate-parity halves AND layer 2
//    (R14's 3 live copies squeezed arch VGPRs to 64 -> 33 MB spill)
// sW block-shared (staged once), sH wave-private, no __syncthreads in t-loop.

__global__ __launch_bounds__(256, 4) void lstm2_mfma(
    const float* __restrict__ x,
    const float* __restrict__ w_ih1, const float* __restrict__ w_hh1,
    const float* __restrict__ b_ih1, const float* __restrict__ b_hh1,
    const float* __restrict__ w_ih2, const float* __restrict__ w_hh2,
    const float* __restrict__ b_ih2, const float* __restrict__ b_hh2,
    float* __restrict__ out, int batch)
{
    __shared__ uint4 sW[20][64];         // 20 KiB: weight B-fragments
    __shared__ uint  sH[4][BPW * ROWU];  // 10 KiB: [h1|h2] f16 state, wave-private
    __shared__ float sB1[8 * 16];        // pre-scaled (b_ih1+b_hh1), [tau][j16]
    __shared__ float sB2[4 * 16];        // pre-scaled (b_ih2+b_hh2), [t2][j16]

    const int tid = threadIdx.x;
    const int w   = tid >> 6;        // wave id
    const int l   = tid & 63;        // lane
    const int q   = l >> 4;          // quarter (k-slice 8q..8q+7)
    const int r16 = l & 15;          // row (A) / col (B,C) within 16x16 tile
    const int wb  = blockIdx.x * 128 + w * BPW;

    // ---- zero sH (h=0 init); wave-private ----
    for (int i = l; i < BPW * ROWU; i += 64) sH[w][i] = 0u;

    // ---- x pointers (clamped rows) ----
    int row0 = wb + r16;      if (row0 > batch - 1) row0 = batch - 1;
    int row1 = wb + 16 + r16; if (row1 > batch - 1) row1 = batch - 1;
    const float* __restrict__ xp0 = x + (size_t)row0 * (T * NF) + q * 8;
    const float* __restrict__ xp1 = x + (size_t)row1 * (T * NF) + q * 8;
    const bool q3 = (q == 3);
    const float2 z2 = make_float2(0.0f, 0.0f);

    // ---- cooperative weight staging (pre-scaled): wave w does tiles w,w+4,.. ----
    for (int tile = w; tile < 20; tile += 4) {
        f16x8 bf;
        if (tile < 16) {
            const int tau  = tile & 7;
            const int gate = tau >> 1, j = (tau & 1) * 16 + r16;
            const bool jv  = (j < H1);
            const int row  = gate * H1 + (jv ? j : 0);
            const bool ih  = (tile < 8);
            const float sc = (gate == 2) ? TWO_L2E : L2E;
            #pragma unroll
            for (int e = 0; e < 8; ++e) {
                const int k = q * 8 + e;
                float v = 0.0f;
                if (ih) { if (jv && k < NF) v = w_ih1[row * NF + k]; }
                else    { if (jv && k < H1) v = w_hh1[row * H1 + k]; }
                bf[e] = (_Float16)(v * sc);
            }
        } else {
            const int t2  = tile - 16;
            const bool jv = (r16 < H2);
            const int row = t2 * H2 + (jv ? r16 : 0);
            const float sc = (t2 == 2) ? TWO_L2E : L2E;
            #pragma unroll
            for (int e = 0; e < 8; ++e) {
                const int k = q * 8 + e;
                float v = 0.0f;
                if (jv) v = (k < H1) ? w_ih2[row * H1 + k] : w_hh2[row * H2 + (k - H1)];
                bf[e] = (_Float16)(v * sc);
            }
        }
        Q u; u.h = bf;
        sW[tile][l] = u.u;
    }

    // ---- biases -> LDS (pre-scaled) ----
    if (tid < 128) {
        const int tau = tid >> 4, col = tid & 15;
        const int gate = tau >> 1, j = (tau & 1) * 16 + col;
        const bool jv = (j < H1);
        const int row = gate * H1 + (jv ? j : 0);
        const float sc = (gate == 2) ? TWO_L2E : L2E;
        sB1[tid] = jv ? (b_ih1[row] + b_hh1[row]) * sc : 0.0f;
    } else if (tid < 192) {
        const int idx = tid - 128;
        const int t2 = idx >> 4, col = idx & 15;
        const bool jv = (col < H2);
        const int row = t2 * H2 + (jv ? col : 0);
        const float sc = (t2 == 2) ? TWO_L2E : L2E;
        sB2[idx] = jv ? (b_ih2[row] + b_hh2[row]) * sc : 0.0f;
    }

    __syncthreads();   // weights+biases visible (only barrier in kernel)

    float c1a[2][4] = {}, c1b[2][4] = {}, c2s[2][4] = {};
    const uint4* HQ = reinterpret_cast<const uint4*>(&sH[w][0]);
    _Float16*   Hh  = reinterpret_cast<_Float16*>(&sH[w][0]);

    #pragma unroll 1
    for (int t = 0; t < T; ++t) {
        // ---- JIT x load + convert ----
        Q xa[2];
        #pragma unroll
        for (int m = 0; m < 2; ++m) {
            const float* __restrict__ p = (m ? xp1 : xp0) + t * NF;
            float2 v0 = *reinterpret_cast<const float2*>(p);
            float2 v1 = q3 ? z2 : *reinterpret_cast<const float2*>(p + 2);
            float2 v2 = q3 ? z2 : *reinterpret_cast<const float2*>(p + 4);
            float2 v3 = q3 ? z2 : *reinterpret_cast<const float2*>(p + 6);
            uint4 u;
            u.x = pkrtz(v0.x, v0.y);
            u.y = pkrtz(v1.x, v1.y);
            u.z = pkrtz(v2.x, v2.y);
            u.w = pkrtz(v3.x, v3.y);
            xa[m].u = u;
        }

        // ---- read [h1|h2](prev t) A-frags ----
        Q ha[2];
        #pragma unroll
        for (int m = 0; m < 2; ++m) ha[m].u = HQ[(m * 16 + r16) * 5 + q];
        __builtin_amdgcn_sched_barrier(0);   // frag reads before h1 overwrite (WAR)

        // ---- ONE accumulator block reused by all three phases ----
        f32x4 acc[2][4];

        // ---- layer 1 in two gate-parity halves (32-reg acc, shared) ----
        #pragma unroll
        for (int h = 0; h < 2; ++h) {        // h=0: j=r16 ; h=1: j=16+r16
            #pragma unroll
            for (int g = 0; g < 4; ++g) {
                const float b = sB1[(2 * g + h) * 16 + r16];
                f32x4 bv = {b, b, b, b};
                acc[0][g] = bv;
                acc[1][g] = bv;
            }
            #pragma unroll
            for (int g = 0; g < 4; ++g) {
                const int tau = 2 * g + h;
                Q wi, wh;
                wi.u = sW[tau][l];          // each fragment read once per t
                wh.u = sW[8 + tau][l];
                acc[0][g] = __builtin_amdgcn_mfma_f32_16x16x32_f16(xa[0].h, wi.h, acc[0][g], 0, 0, 0);
                acc[1][g] = __builtin_amdgcn_mfma_f32_16x16x32_f16(xa[1].h, wi.h, acc[1][g], 0, 0, 0);
                acc[0][g] = __builtin_amdgcn_mfma_f32_16x16x32_f16(ha[0].h, wh.h, acc[0][g], 0, 0, 0);
                acc[1][g] = __builtin_amdgcn_mfma_f32_16x16x32_f16(ha[1].h, wh.h, acc[1][g], 0, 0, 0);
                if (g == 1) __builtin_amdgcn_sched_barrier(0);  // cap frag window
            }
            __builtin_amdgcn_sched_barrier(0);
            #pragma unroll
            for (int m = 0; m < 2; ++m) {
                #pragma unroll
                for (int r = 0; r < 4; ++r) {
                    const int lrow = m * 16 + q * 4 + r;  // C row = 4*(l>>4)+reg (m89)
                    float& cref = (h == 0) ? c1a[m][r] : c1b[m][r];
                    const float hv = cellp(acc[m][0][r], acc[m][1][r], acc[m][2][r], acc[m][3][r], cref);
                    if (h == 0) Hh[lrow * 40 + r16] = (_Float16)hv;
                    else if (r16 < 8) Hh[lrow * 40 + 16 + r16] = (_Float16)hv;
                }
            }
            __builtin_amdgcn_sched_barrier(0);
        }

        // ---- layer 2: A = [h1(t) | h2(t-1)], same acc block ----
        Q hc[2];
        #pragma unroll
        for (int m = 0; m < 2; ++m) hc[m].u = HQ[(m * 16 + r16) * 5 + q];
        __builtin_amdgcn_sched_barrier(0);   // hc reads before h2 overwrite (WAR)
        #pragma unroll
        for (int t2 = 0; t2 < 4; ++t2) {
            const float b = sB2[t2 * 16 + r16];
            f32x4 bv = {b, b, b, b};
            acc[0][t2] = bv;
            acc[1][t2] = bv;
        }
        #pragma unroll
        for (int t2 = 0; t2 < 4; ++t2) {
            Q wc; wc.u = sW[16 + t2][l];
            acc[0][t2] = __builtin_amdgcn_mfma_f32_16x16x32_f16(hc[0].h, wc.h, acc[0][t2], 0, 0, 0);
            acc[1][t2] = __builtin_amdgcn_mfma_f32_16x16x32_f16(hc[1].h, wc.h, acc[1][t2], 0, 0, 0);
        }
        __builtin_amdgcn_sched_barrier(0);
        #pragma unroll
        for (int m = 0; m < 2; ++m) {
            #pragma unroll
            for (int r = 0; r < 4; ++r) {
                const int lrow = m * 16 + q * 4 + r;
                const float h2v = cellp(acc[m][0][r], acc[m][1][r], acc[m][2][r], acc[m][3][r], c2s[m][r]);
                if (r16 < 8) Hh[lrow * 40 + 24 + r16] = (_Float16)h2v; // h2 cols 24..31
            }
        }
        __builtin_amdgcn_sched_barrier(0);   // h2 writes before next-t ha reads (RAW)
    }

    // ---- epilogue: read final h2 from sH, coalesced float4 out ----
    {
        const int erow = l >> 1, ecg = l & 1;
        const uint2 hv = *reinterpret_cast<const uint2*>(&Hh[erow * 40 + 24 + ecg * 4]);
        union { uint u; fp16x2 p; } a0, a1;
        a0.u = hv.x; a1.u = hv.y;
        const int orow = wb + erow;
        if (orow < batch) {
            float4 o = make_float4((float)a0.p[0], (float)a0.p[1],
                                   (float)a1.p[0], (float)a1.p[1]);
            *reinterpret_cast<float4*>(out + (size_t)orow * H2 + ecg * 4) = o;
        }
    }
}

extern "C" void kernel_launch(void* const* d_in, const int* in_sizes, int n_in,
                              void* d_out, int out_size, void* d_ws, size_t ws_size,
                              hipStream_t stream)
{
    const float* x     = (const float*)d_in[0];
    const float* w_ih1 = (const float*)d_in[1];
    const float* w_hh1 = (const float*)d_in[2];
    const float* b_ih1 = (const float*)d_in[3];
    const float* b_hh1 = (const float*)d_in[4];
    const float* w_ih2 = (const float*)d_in[5];
    const float* w_hh2 = (const float*)d_in[6];
    const float* b_ih2 = (const float*)d_in[7];
    const float* b_hh2 = (const float*)d_in[8];
    float* out = (float*)d_out;

    const int batch = in_sizes[0] / (T * NF);
    const int block = 256;                    // 4 waves x 32 batch rows
    const int grid  = (batch + 127) / 128;
    lstm2_mfma<<<grid, block, 0, stream>>>(x, w_ih1, w_hh1, b_ih1, b_hh1,
                                           w_ih2, w_hh2, b_ih2, b_hh2,
                                           out, batch);
}

// Round 17
// 71.523 us; speedup vs baseline: 4.1056x; 1.1943x over previous
//
#include <hip/hip_runtime.h>

#define DEV_INLINE __device__ __forceinline__

constexpr int NF = 26;   // input features
constexpr int H1 = 24;   // layer-1 hidden
constexpr int H2 = 8;    // layer-2 hidden
constexpr int T  = 5;    // sequence length
constexpr int BPW  = 32; // batch rows per wave (2 M-tiles of 16)
constexpr int ROWU = 20; // uints per LDS h-row (40 f16 = 80 B)

constexpr float L2E     = 1.44269504088896f;   // log2(e)
constexpr float TWO_L2E = 2.88539008177792f;   // 2*log2(e)

typedef _Float16 f16x8 __attribute__((ext_vector_type(8)));
typedef float    f32x4 __attribute__((ext_vector_type(4)));
typedef __fp16   fp16x2 __attribute__((ext_vector_type(2)));

union Q { uint4 u; f16x8 h; };

DEV_INLINE float fast_rcp(float x) { return __builtin_amdgcn_rcpf(x); }
// 1/(1+2^-x); with pre-scaled gate a = log2e*raw this IS sigmoid(raw).
DEV_INLINE float rcp1p(float x) { return fast_rcp(1.0f + __builtin_amdgcn_exp2f(-x)); }
// cell with PRE-SCALED gates: i,f,o scaled by log2e; g scaled by 2*log2e.
DEV_INLINE float cellp(float i_, float f_, float g_, float o_, float& c) {
    const float ig = rcp1p(i_), fg = rcp1p(f_);
    const float gg = fmaf(2.0f, rcp1p(g_), -1.0f);   // tanh(raw g)
    const float og = rcp1p(o_);
    c = fmaf(fg, c, ig * gg);
    return og * fmaf(2.0f, rcp1p(c * TWO_L2E), -1.0f);   // o*tanh(c)
}
DEV_INLINE uint pkrtz(float a, float b) {
    union { uint u; fp16x2 p; } v; v.p = __builtin_amdgcn_cvt_pkrtz(a, b); return v.u;
}
// lane^8 exchange (BitMode: xor=8,or=0,and=0x1F). CONVERGENT: must be called
// unconditionally by all lanes (R16 bug: calling it inside the ternary put it
// under divergent exec -> source lanes disabled -> undefined data).
DEV_INLINE float swz8(float v) {
    union { float f; int i; } a, b;
    a.f = v;
    b.i = __builtin_amdgcn_ds_swizzle(a.i, 0x201F);
    return b.f;
}

// R17 = R16 with the swizzles hoisted OUT of the conditionals (convergence fix).
//  * h1-odd and L2 cell batches merged across m -> 4 full-lane cellp batches/t
//  * __launch_bounds__(256,5): 5 blocks/CU (LDS 5x31744 <= 160 KiB)
//  * log2e pre-scaled weights/biases; exp2-based cells
// sW block-shared (staged once), sH wave-private, no __syncthreads in t-loop.

__global__ __launch_bounds__(256, 5) void lstm2_mfma(
    const float* __restrict__ x,
    const float* __restrict__ w_ih1, const float* __restrict__ w_hh1,
    const float* __restrict__ b_ih1, const float* __restrict__ b_hh1,
    const float* __restrict__ w_ih2, const float* __restrict__ w_hh2,
    const float* __restrict__ b_ih2, const float* __restrict__ b_hh2,
    float* __restrict__ out, int batch)
{
    __shared__ uint4 sW[20][64];         // 20 KiB: weight B-fragments
    __shared__ uint  sH[4][BPW * ROWU];  // 10 KiB: [h1|h2] f16 state, wave-private
    __shared__ float sB1[8 * 16];        // pre-scaled (b_ih1+b_hh1), [tau][j16]
    __shared__ float sB2[4 * 16];        // pre-scaled (b_ih2+b_hh2), [t2][j16]

    const int tid = threadIdx.x;
    const int w   = tid >> 6;        // wave id
    const int l   = tid & 63;        // lane
    const int q   = l >> 4;          // quarter (k-slice 8q..8q+7)
    const int r16 = l & 15;          // row (A) / col (B,C) within 16x16 tile
    const bool lo = (r16 < 8);
    const int wb  = blockIdx.x * 128 + w * BPW;

    // ---- zero sH (h=0 init); wave-private ----
    for (int i = l; i < BPW * ROWU; i += 64) sH[w][i] = 0u;

    // ---- x pointers (clamped rows) ----
    int row0 = wb + r16;      if (row0 > batch - 1) row0 = batch - 1;
    int row1 = wb + 16 + r16; if (row1 > batch - 1) row1 = batch - 1;
    const float* __restrict__ xp0 = x + (size_t)row0 * (T * NF) + q * 8;
    const float* __restrict__ xp1 = x + (size_t)row1 * (T * NF) + q * 8;
    const bool q3 = (q == 3);
    const float2 z2 = make_float2(0.0f, 0.0f);

    // ---- cooperative weight staging (pre-scaled): wave w does tiles w,w+4,.. ----
    for (int tile = w; tile < 20; tile += 4) {
        f16x8 bf;
        if (tile < 16) {
            const int tau  = tile & 7;
            const int gate = tau >> 1, j = (tau & 1) * 16 + r16;
            const bool jv  = (j < H1);
            const int row  = gate * H1 + (jv ? j : 0);
            const bool ih  = (tile < 8);
            const float sc = (gate == 2) ? TWO_L2E : L2E;
            #pragma unroll
            for (int e = 0; e < 8; ++e) {
                const int k = q * 8 + e;
                float v = 0.0f;
                if (ih) { if (jv && k < NF) v = w_ih1[row * NF + k]; }
                else    { if (jv && k < H1) v = w_hh1[row * H1 + k]; }
                bf[e] = (_Float16)(v * sc);
            }
        } else {
            const int t2  = tile - 16;
            const bool jv = (r16 < H2);
            const int row = t2 * H2 + (jv ? r16 : 0);
            const float sc = (t2 == 2) ? TWO_L2E : L2E;
            #pragma unroll
            for (int e = 0; e < 8; ++e) {
                const int k = q * 8 + e;
                float v = 0.0f;
                if (jv) v = (k < H1) ? w_ih2[row * H1 + k] : w_hh2[row * H2 + (k - H1)];
                bf[e] = (_Float16)(v * sc);
            }
        }
        Q u; u.h = bf;
        sW[tile][l] = u.u;
    }

    // ---- biases -> LDS (pre-scaled) ----
    if (tid < 128) {
        const int tau = tid >> 4, col = tid & 15;
        const int gate = tau >> 1, j = (tau & 1) * 16 + col;
        const bool jv = (j < H1);
        const int row = gate * H1 + (jv ? j : 0);
        const float sc = (gate == 2) ? TWO_L2E : L2E;
        sB1[tid] = jv ? (b_ih1[row] + b_hh1[row]) * sc : 0.0f;
    } else if (tid < 192) {
        const int idx = tid - 128;
        const int t2 = idx >> 4, col = idx & 15;
        const bool jv = (col < H2);
        const int row = t2 * H2 + (jv ? col : 0);
        const float sc = (t2 == 2) ? TWO_L2E : L2E;
        sB2[idx] = jv ? (b_ih2[row] + b_hh2[row]) * sc : 0.0f;
    }

    __syncthreads();   // weights+biases visible (only barrier in kernel)

    // c-state: even half per-m (all lanes); merged halves per-lane single m
    float c1a[2][4] = {}, c1b[4] = {}, c2s[4] = {};
    const uint4* HQ = reinterpret_cast<const uint4*>(&sH[w][0]);
    _Float16*   Hh  = reinterpret_cast<_Float16*>(&sH[w][0]);

    #pragma unroll 1
    for (int t = 0; t < T; ++t) {
        // ---- JIT x load + convert ----
        Q xa[2];
        #pragma unroll
        for (int m = 0; m < 2; ++m) {
            const float* __restrict__ p = (m ? xp1 : xp0) + t * NF;
            float2 v0 = *reinterpret_cast<const float2*>(p);
            float2 v1 = q3 ? z2 : *reinterpret_cast<const float2*>(p + 2);
            float2 v2 = q3 ? z2 : *reinterpret_cast<const float2*>(p + 4);
            float2 v3 = q3 ? z2 : *reinterpret_cast<const float2*>(p + 6);
            uint4 u;
            u.x = pkrtz(v0.x, v0.y);
            u.y = pkrtz(v1.x, v1.y);
            u.z = pkrtz(v2.x, v2.y);
            u.w = pkrtz(v3.x, v3.y);
            xa[m].u = u;
        }

        // ---- read [h1|h2](prev t) A-frags ----
        Q ha[2];
        #pragma unroll
        for (int m = 0; m < 2; ++m) ha[m].u = HQ[(m * 16 + r16) * 5 + q];
        __builtin_amdgcn_sched_barrier(0);   // frag reads before h1 overwrite (WAR)

        f32x4 acc[2][4];                     // one block reused by all phases

        // ---- layer 1, even half (cols j=r16, full lanes, per-m cells) ----
        #pragma unroll
        for (int g = 0; g < 4; ++g) {
            const float b = sB1[(2 * g) * 16 + r16];
            f32x4 bv = {b, b, b, b};
            acc[0][g] = bv;
            acc[1][g] = bv;
        }
        #pragma unroll
        for (int g = 0; g < 4; ++g) {
            const int tau = 2 * g;
            Q wi, wh;
            wi.u = sW[tau][l];
            wh.u = sW[8 + tau][l];
            acc[0][g] = __builtin_amdgcn_mfma_f32_16x16x32_f16(xa[0].h, wi.h, acc[0][g], 0, 0, 0);
            acc[1][g] = __builtin_amdgcn_mfma_f32_16x16x32_f16(xa[1].h, wi.h, acc[1][g], 0, 0, 0);
            acc[0][g] = __builtin_amdgcn_mfma_f32_16x16x32_f16(ha[0].h, wh.h, acc[0][g], 0, 0, 0);
            acc[1][g] = __builtin_amdgcn_mfma_f32_16x16x32_f16(ha[1].h, wh.h, acc[1][g], 0, 0, 0);
            if (g == 1) __builtin_amdgcn_sched_barrier(0);  // cap frag window
        }
        __builtin_amdgcn_sched_barrier(0);
        #pragma unroll
        for (int m = 0; m < 2; ++m) {
            #pragma unroll
            for (int r = 0; r < 4; ++r) {
                const int lrow = m * 16 + q * 4 + r;        // C row = 4*(l>>4)+reg
                const float hv = cellp(acc[m][0][r], acc[m][1][r], acc[m][2][r], acc[m][3][r], c1a[m][r]);
                Hh[lrow * 40 + r16] = (_Float16)hv;         // col j = r16
            }
        }
        __builtin_amdgcn_sched_barrier(0);

        // ---- layer 1, odd half (cols 16..23): MERGED across m (full lanes) ----
        #pragma unroll
        for (int g = 0; g < 4; ++g) {
            const float b = sB1[(2 * g + 1) * 16 + r16];
            f32x4 bv = {b, b, b, b};
            acc[0][g] = bv;
            acc[1][g] = bv;
        }
        #pragma unroll
        for (int g = 0; g < 4; ++g) {
            const int tau = 2 * g + 1;
            Q wi, wh;
            wi.u = sW[tau][l];
            wh.u = sW[8 + tau][l];
            acc[0][g] = __builtin_amdgcn_mfma_f32_16x16x32_f16(xa[0].h, wi.h, acc[0][g], 0, 0, 0);
            acc[1][g] = __builtin_amdgcn_mfma_f32_16x16x32_f16(xa[1].h, wi.h, acc[1][g], 0, 0, 0);
            acc[0][g] = __builtin_amdgcn_mfma_f32_16x16x32_f16(ha[0].h, wh.h, acc[0][g], 0, 0, 0);
            acc[1][g] = __builtin_amdgcn_mfma_f32_16x16x32_f16(ha[1].h, wh.h, acc[1][g], 0, 0, 0);
            if (g == 1) __builtin_amdgcn_sched_barrier(0);
        }
        __builtin_amdgcn_sched_barrier(0);
        #pragma unroll
        for (int r = 0; r < 4; ++r) {
            // ALL lanes run the swizzle (convergent); select afterwards.
            const float si = swz8(acc[1][0][r]);
            const float sf = swz8(acc[1][1][r]);
            const float sg = swz8(acc[1][2][r]);
            const float so = swz8(acc[1][3][r]);
            const float i_ = lo ? acc[0][0][r] : si;
            const float f_ = lo ? acc[0][1][r] : sf;
            const float g_ = lo ? acc[0][2][r] : sg;
            const float o_ = lo ? acc[0][3][r] : so;
            const float hv = cellp(i_, f_, g_, o_, c1b[r]);
            const int lrow = (lo ? 0 : 16) + q * 4 + r;
            Hh[lrow * 40 + 16 + (r16 & 7)] = (_Float16)hv;
        }
        __builtin_amdgcn_sched_barrier(0);   // h1 writes before hc reads (RAW)

        // ---- layer 2: A = [h1(t) | h2(t-1)]; cells MERGED across m ----
        Q hc[2];
        #pragma unroll
        for (int m = 0; m < 2; ++m) hc[m].u = HQ[(m * 16 + r16) * 5 + q];
        __builtin_amdgcn_sched_barrier(0);   // hc reads before h2 overwrite (WAR)
        #pragma unroll
        for (int t2 = 0; t2 < 4; ++t2) {
            const float b = sB2[t2 * 16 + r16];
            f32x4 bv = {b, b, b, b};
            acc[0][t2] = bv;
            acc[1][t2] = bv;
        }
        #pragma unroll
        for (int t2 = 0; t2 < 4; ++t2) {
            Q wc; wc.u = sW[16 + t2][l];
            acc[0][t2] = __builtin_amdgcn_mfma_f32_16x16x32_f16(hc[0].h, wc.h, acc[0][t2], 0, 0, 0);
            acc[1][t2] = __builtin_amdgcn_mfma_f32_16x16x32_f16(hc[1].h, wc.h, acc[1][t2], 0, 0, 0);
        }
        __builtin_amdgcn_sched_barrier(0);
        #pragma unroll
        for (int r = 0; r < 4; ++r) {
            const float si = swz8(acc[1][0][r]);
            const float sf = swz8(acc[1][1][r]);
            const float sg = swz8(acc[1][2][r]);
            const float so = swz8(acc[1][3][r]);
            const float i_ = lo ? acc[0][0][r] : si;
            const float f_ = lo ? acc[0][1][r] : sf;
            const float g_ = lo ? acc[0][2][r] : sg;
            const float o_ = lo ? acc[0][3][r] : so;
            const float h2v = cellp(i_, f_, g_, o_, c2s[r]);
            const int lrow = (lo ? 0 : 16) + q * 4 + r;
            Hh[lrow * 40 + 24 + (r16 & 7)] = (_Float16)h2v;   // h2 cols 24..31
        }
        __builtin_amdgcn_sched_barrier(0);   // h2 writes before next-t ha reads (RAW)
    }

    // ---- epilogue: read final h2 from sH, coalesced float4 out ----
    {
        const int erow = l >> 1, ecg = l & 1;
        const uint2 hv = *reinterpret_cast<const uint2*>(&Hh[erow * 40 + 24 + ecg * 4]);
        union { uint u; fp16x2 p; } a0, a1;
        a0.u = hv.x; a1.u = hv.y;
        const int orow = wb + erow;
        if (orow < batch) {
            float4 o = make_float4((float)a0.p[0], (float)a0.p[1],
                                   (float)a1.p[0], (float)a1.p[1]);
            *reinterpret_cast<float4*>(out + (size_t)orow * H2 + ecg * 4) = o;
        }
    }
}

extern "C" void kernel_launch(void* const* d_in, const int* in_sizes, int n_in,
                              void* d_out, int out_size, void* d_ws, size_t ws_size,
                              hipStream_t stream)
{
    const float* x     = (const float*)d_in[0];
    const float* w_ih1 = (const float*)d_in[1];
    const float* w_hh1 = (const float*)d_in[2];
    const float* b_ih1 = (const float*)d_in[3];
    const float* b_hh1 = (const float*)d_in[4];
    const float* w_ih2 = (const float*)d_in[5];
    const float* w_hh2 = (const float*)d_in[6];
    const float* b_ih2 = (const float*)d_in[7];
    const float* b_hh2 = (const float*)d_in[8];
    float* out = (float*)d_out;

    const int batch = in_sizes[0] / (T * NF);
    const int block = 256;                    // 4 waves x 32 batch rows
    const int grid  = (batch + 127) / 128;
    lstm2_mfma<<<grid, block, 0, stream>>>(x, w_ih1, w_hh1, b_ih1, b_hh1,
                                           w_ih2, w_hh2, b_ih2, b_hh2,
                                           out, batch);
}

// Round 18
// 70.610 us; speedup vs baseline: 4.1586x; 1.0129x over previous
//
#include <hip/hip_runtime.h>

#define DEV_INLINE __device__ __forceinline__

constexpr int NF = 26;   // input features
constexpr int H1 = 24;   // layer-1 hidden
constexpr int H2 = 8;    // layer-2 hidden
constexpr int T  = 5;    // sequence length
constexpr int BPW  = 32; // batch rows per wave (2 M-tiles of 16)
constexpr int ROWU = 20; // uints per LDS h-row (40 f16 = 80 B)
constexpr int WPB  = 8;  // waves per block (512 threads)

constexpr float L2E     = 1.44269504088896f;   // log2(e)
constexpr float TWO_L2E = 2.88539008177792f;   // 2*log2(e)

typedef _Float16 f16x8 __attribute__((ext_vector_type(8)));
typedef float    f32x4 __attribute__((ext_vector_type(4)));
typedef __fp16   fp16x2 __attribute__((ext_vector_type(2)));

union Q { uint4 u; f16x8 h; };

DEV_INLINE float fast_rcp(float x) { return __builtin_amdgcn_rcpf(x); }
// 1/(1+2^-x); with pre-scaled gate a = log2e*raw this IS sigmoid(raw).
DEV_INLINE float rcp1p(float x) { return fast_rcp(1.0f + __builtin_amdgcn_exp2f(-x)); }
// cell with PRE-SCALED gates: i,f,o scaled by log2e; g scaled by 2*log2e.
DEV_INLINE float cellp(float i_, float f_, float g_, float o_, float& c) {
    const float ig = rcp1p(i_), fg = rcp1p(f_);
    const float gg = fmaf(2.0f, rcp1p(g_), -1.0f);   // tanh(raw g)
    const float og = rcp1p(o_);
    c = fmaf(fg, c, ig * gg);
    return og * fmaf(2.0f, rcp1p(c * TWO_L2E), -1.0f);   // o*tanh(c)
}
DEV_INLINE uint pkrtz(float a, float b) {
    union { uint u; fp16x2 p; } v; v.p = __builtin_amdgcn_cvt_pkrtz(a, b); return v.u;
}
// lane^8 exchange (BitMode: xor=8,or=0,and=0x1F). CONVERGENT: call on all lanes.
DEV_INLINE float swz8(float v) {
    union { float f; int i; } a, b;
    a.f = v;
    b.i = __builtin_amdgcn_ds_swizzle(a.i, 0x201F);
    return b.f;
}

// R18 = R17 with 512-thread blocks (8 waves) to amortize the 20 KB sW over
// twice as many waves: LDS/block = 41.7 KB -> 3 blocks/CU x 8 waves =
// 6 waves/SIMD (was 5 blocks x 4 = achieved ~3.2). __launch_bounds__(512,6)
// caps unified regs at 85 >= measured 80 -> no spill expected.
// Body identical to R17 (merged full-lane cells, log2e pre-scale, exp2 cells,
// sW block-shared, sH wave-private, no __syncthreads in t-loop).

__global__ __launch_bounds__(512, 6) void lstm2_mfma(
    const float* __restrict__ x,
    const float* __restrict__ w_ih1, const float* __restrict__ w_hh1,
    const float* __restrict__ b_ih1, const float* __restrict__ b_hh1,
    const float* __restrict__ w_ih2, const float* __restrict__ w_hh2,
    const float* __restrict__ b_ih2, const float* __restrict__ b_hh2,
    float* __restrict__ out, int batch)
{
    __shared__ uint4 sW[20][64];           // 20 KiB: weight B-fragments
    __shared__ uint  sH[WPB][BPW * ROWU];  // 20 KiB: [h1|h2] f16 state, wave-private
    __shared__ float sB1[8 * 16];          // pre-scaled (b_ih1+b_hh1), [tau][j16]
    __shared__ float sB2[4 * 16];          // pre-scaled (b_ih2+b_hh2), [t2][j16]

    const int tid = threadIdx.x;
    const int w   = tid >> 6;        // wave id (0..7)
    const int l   = tid & 63;        // lane
    const int q   = l >> 4;          // quarter (k-slice 8q..8q+7)
    const int r16 = l & 15;          // row (A) / col (B,C) within 16x16 tile
    const bool lo = (r16 < 8);
    const int wb  = blockIdx.x * (WPB * BPW) + w * BPW;

    // ---- zero sH (h=0 init); wave-private ----
    for (int i = l; i < BPW * ROWU; i += 64) sH[w][i] = 0u;

    // ---- x pointers (clamped rows) ----
    int row0 = wb + r16;      if (row0 > batch - 1) row0 = batch - 1;
    int row1 = wb + 16 + r16; if (row1 > batch - 1) row1 = batch - 1;
    const float* __restrict__ xp0 = x + (size_t)row0 * (T * NF) + q * 8;
    const float* __restrict__ xp1 = x + (size_t)row1 * (T * NF) + q * 8;
    const bool q3 = (q == 3);
    const float2 z2 = make_float2(0.0f, 0.0f);

    // ---- cooperative weight staging (pre-scaled): wave w does tiles w,w+8,.. ----
    for (int tile = w; tile < 20; tile += WPB) {
        f16x8 bf;
        if (tile < 16) {
            const int tau  = tile & 7;
            const int gate = tau >> 1, j = (tau & 1) * 16 + r16;
            const bool jv  = (j < H1);
            const int row  = gate * H1 + (jv ? j : 0);
            const bool ih  = (tile < 8);
            const float sc = (gate == 2) ? TWO_L2E : L2E;
            #pragma unroll
            for (int e = 0; e < 8; ++e) {
                const int k = q * 8 + e;
                float v = 0.0f;
                if (ih) { if (jv && k < NF) v = w_ih1[row * NF + k]; }
                else    { if (jv && k < H1) v = w_hh1[row * H1 + k]; }
                bf[e] = (_Float16)(v * sc);
            }
        } else {
            const int t2  = tile - 16;
            const bool jv = (r16 < H2);
            const int row = t2 * H2 + (jv ? r16 : 0);
            const float sc = (t2 == 2) ? TWO_L2E : L2E;
            #pragma unroll
            for (int e = 0; e < 8; ++e) {
                const int k = q * 8 + e;
                float v = 0.0f;
                if (jv) v = (k < H1) ? w_ih2[row * H1 + k] : w_hh2[row * H2 + (k - H1)];
                bf[e] = (_Float16)(v * sc);
            }
        }
        Q u; u.h = bf;
        sW[tile][l] = u.u;
    }

    // ---- biases -> LDS (pre-scaled) ----
    if (tid < 128) {
        const int tau = tid >> 4, col = tid & 15;
        const int gate = tau >> 1, j = (tau & 1) * 16 + col;
        const bool jv = (j < H1);
        const int row = gate * H1 + (jv ? j : 0);
        const float sc = (gate == 2) ? TWO_L2E : L2E;
        sB1[tid] = jv ? (b_ih1[row] + b_hh1[row]) * sc : 0.0f;
    } else if (tid < 192) {
        const int idx = tid - 128;
        const int t2 = idx >> 4, col = idx & 15;
        const bool jv = (col < H2);
        const int row = t2 * H2 + (jv ? col : 0);
        const float sc = (t2 == 2) ? TWO_L2E : L2E;
        sB2[idx] = jv ? (b_ih2[row] + b_hh2[row]) * sc : 0.0f;
    }

    __syncthreads();   // weights+biases visible (only barrier in kernel)

    // c-state: even half per-m (all lanes); merged halves per-lane single m
    float c1a[2][4] = {}, c1b[4] = {}, c2s[4] = {};
    const uint4* HQ = reinterpret_cast<const uint4*>(&sH[w][0]);
    _Float16*   Hh  = reinterpret_cast<_Float16*>(&sH[w][0]);

    #pragma unroll 1
    for (int t = 0; t < T; ++t) {
        // ---- JIT x load + convert ----
        Q xa[2];
        #pragma unroll
        for (int m = 0; m < 2; ++m) {
            const float* __restrict__ p = (m ? xp1 : xp0) + t * NF;
            float2 v0 = *reinterpret_cast<const float2*>(p);
            float2 v1 = q3 ? z2 : *reinterpret_cast<const float2*>(p + 2);
            float2 v2 = q3 ? z2 : *reinterpret_cast<const float2*>(p + 4);
            float2 v3 = q3 ? z2 : *reinterpret_cast<const float2*>(p + 6);
            uint4 u;
            u.x = pkrtz(v0.x, v0.y);
            u.y = pkrtz(v1.x, v1.y);
            u.z = pkrtz(v2.x, v2.y);
            u.w = pkrtz(v3.x, v3.y);
            xa[m].u = u;
        }

        // ---- read [h1|h2](prev t) A-frags ----
        Q ha[2];
        #pragma unroll
        for (int m = 0; m < 2; ++m) ha[m].u = HQ[(m * 16 + r16) * 5 + q];
        __builtin_amdgcn_sched_barrier(0);   // frag reads before h1 overwrite (WAR)

        f32x4 acc[2][4];                     // one block reused by all phases

        // ---- layer 1, even half (cols j=r16, full lanes, per-m cells) ----
        #pragma unroll
        for (int g = 0; g < 4; ++g) {
            const float b = sB1[(2 * g) * 16 + r16];
            f32x4 bv = {b, b, b, b};
            acc[0][g] = bv;
            acc[1][g] = bv;
        }
        #pragma unroll
        for (int g = 0; g < 4; ++g) {
            const int tau = 2 * g;
            Q wi, wh;
            wi.u = sW[tau][l];
            wh.u = sW[8 + tau][l];
            acc[0][g] = __builtin_amdgcn_mfma_f32_16x16x32_f16(xa[0].h, wi.h, acc[0][g], 0, 0, 0);
            acc[1][g] = __builtin_amdgcn_mfma_f32_16x16x32_f16(xa[1].h, wi.h, acc[1][g], 0, 0, 0);
            acc[0][g] = __builtin_amdgcn_mfma_f32_16x16x32_f16(ha[0].h, wh.h, acc[0][g], 0, 0, 0);
            acc[1][g] = __builtin_amdgcn_mfma_f32_16x16x32_f16(ha[1].h, wh.h, acc[1][g], 0, 0, 0);
            if (g == 1) __builtin_amdgcn_sched_barrier(0);  // cap frag window
        }
        __builtin_amdgcn_sched_barrier(0);
        #pragma unroll
        for (int m = 0; m < 2; ++m) {
            #pragma unroll
            for (int r = 0; r < 4; ++r) {
                const int lrow = m * 16 + q * 4 + r;        // C row = 4*(l>>4)+reg
                const float hv = cellp(acc[m][0][r], acc[m][1][r], acc[m][2][r], acc[m][3][r], c1a[m][r]);
                Hh[lrow * 40 + r16] = (_Float16)hv;         // col j = r16
            }
        }
        __builtin_amdgcn_sched_barrier(0);

        // ---- layer 1, odd half (cols 16..23): MERGED across m (full lanes) ----
        #pragma unroll
        for (int g = 0; g < 4; ++g) {
            const float b = sB1[(2 * g + 1) * 16 + r16];
            f32x4 bv = {b, b, b, b};
            acc[0][g] = bv;
            acc[1][g] = bv;
        }
        #pragma unroll
        for (int g = 0; g < 4; ++g) {
            const int tau = 2 * g + 1;
            Q wi, wh;
            wi.u = sW[tau][l];
            wh.u = sW[8 + tau][l];
            acc[0][g] = __builtin_amdgcn_mfma_f32_16x16x32_f16(xa[0].h, wi.h, acc[0][g], 0, 0, 0);
            acc[1][g] = __builtin_amdgcn_mfma_f32_16x16x32_f16(xa[1].h, wi.h, acc[1][g], 0, 0, 0);
            acc[0][g] = __builtin_amdgcn_mfma_f32_16x16x32_f16(ha[0].h, wh.h, acc[0][g], 0, 0, 0);
            acc[1][g] = __builtin_amdgcn_mfma_f32_16x16x32_f16(ha[1].h, wh.h, acc[1][g], 0, 0, 0);
            if (g == 1) __builtin_amdgcn_sched_barrier(0);
        }
        __builtin_amdgcn_sched_barrier(0);
        #pragma unroll
        for (int r = 0; r < 4; ++r) {
            // ALL lanes run the swizzle (convergent); select afterwards.
            const float si = swz8(acc[1][0][r]);
            const float sf = swz8(acc[1][1][r]);
            const float sg = swz8(acc[1][2][r]);
            const float so = swz8(acc[1][3][r]);
            const float i_ = lo ? acc[0][0][r] : si;
            const float f_ = lo ? acc[0][1][r] : sf;
            const float g_ = lo ? acc[0][2][r] : sg;
            const float o_ = lo ? acc[0][3][r] : so;
            const float hv = cellp(i_, f_, g_, o_, c1b[r]);
            const int lrow = (lo ? 0 : 16) + q * 4 + r;
            Hh[lrow * 40 + 16 + (r16 & 7)] = (_Float16)hv;
        }
        __builtin_amdgcn_sched_barrier(0);   // h1 writes before hc reads (RAW)

        // ---- layer 2: A = [h1(t) | h2(t-1)]; cells MERGED across m ----
        Q hc[2];
        #pragma unroll
        for (int m = 0; m < 2; ++m) hc[m].u = HQ[(m * 16 + r16) * 5 + q];
        __builtin_amdgcn_sched_barrier(0);   // hc reads before h2 overwrite (WAR)
        #pragma unroll
        for (int t2 = 0; t2 < 4; ++t2) {
            const float b = sB2[t2 * 16 + r16];
            f32x4 bv = {b, b, b, b};
            acc[0][t2] = bv;
            acc[1][t2] = bv;
        }
        #pragma unroll
        for (int t2 = 0; t2 < 4; ++t2) {
            Q wc; wc.u = sW[16 + t2][l];
            acc[0][t2] = __builtin_amdgcn_mfma_f32_16x16x32_f16(hc[0].h, wc.h, acc[0][t2], 0, 0, 0);
            acc[1][t2] = __builtin_amdgcn_mfma_f32_16x16x32_f16(hc[1].h, wc.h, acc[1][t2], 0, 0, 0);
        }
        __builtin_amdgcn_sched_barrier(0);
        #pragma unroll
        for (int r = 0; r < 4; ++r) {
            const float si = swz8(acc[1][0][r]);
            const float sf = swz8(acc[1][1][r]);
            const float sg = swz8(acc[1][2][r]);
            const float so = swz8(acc[1][3][r]);
            const float i_ = lo ? acc[0][0][r] : si;
            const float f_ = lo ? acc[0][1][r] : sf;
            const float g_ = lo ? acc[0][2][r] : sg;
            const float o_ = lo ? acc[0][3][r] : so;
            const float h2v = cellp(i_, f_, g_, o_, c2s[r]);
            const int lrow = (lo ? 0 : 16) + q * 4 + r;
            Hh[lrow * 40 + 24 + (r16 & 7)] = (_Float16)h2v;   // h2 cols 24..31
        }
        __builtin_amdgcn_sched_barrier(0);   // h2 writes before next-t ha reads (RAW)
    }

    // ---- epilogue: read final h2 from sH, coalesced float4 out ----
    {
        const int erow = l >> 1, ecg = l & 1;
        const uint2 hv = *reinterpret_cast<const uint2*>(&Hh[erow * 40 + 24 + ecg * 4]);
        union { uint u; fp16x2 p; } a0, a1;
        a0.u = hv.x; a1.u = hv.y;
        const int orow = wb + erow;
        if (orow < batch) {
            float4 o = make_float4((float)a0.p[0], (float)a0.p[1],
                                   (float)a1.p[0], (float)a1.p[1]);
            *reinterpret_cast<float4*>(out + (size_t)orow * H2 + ecg * 4) = o;
        }
    }
}

extern "C" void kernel_launch(void* const* d_in, const int* in_sizes, int n_in,
                              void* d_out, int out_size, void* d_ws, size_t ws_size,
                              hipStream_t stream)
{
    const float* x     = (const float*)d_in[0];
    const float* w_ih1 = (const float*)d_in[1];
    const float* w_hh1 = (const float*)d_in[2];
    const float* b_ih1 = (const float*)d_in[3];
    const float* b_hh1 = (const float*)d_in[4];
    const float* w_ih2 = (const float*)d_in[5];
    const float* w_hh2 = (const float*)d_in[6];
    const float* b_ih2 = (const float*)d_in[7];
    const float* b_hh2 = (const float*)d_in[8];
    float* out = (float*)d_out;

    const int batch = in_sizes[0] / (T * NF);
    const int block = 512;                    // 8 waves x 32 batch rows
    const int rows_per_block = WPB * BPW;     // 256
    const int grid  = (batch + rows_per_block - 1) / rows_per_block;
    lstm2_mfma<<<grid, block, 0, stream>>>(x, w_ih1, w_hh1, b_ih1, b_hh1,
                                           w_ih2, w_hh2, b_ih2, b_hh2,
                                           out, batch);
}